// Round 1
// baseline (295.874 us; speedup 1.0000x reference)
//
#include <hip/hip_runtime.h>
#include <math.h>

#define NN 1024
#define CC 200
#define AA 256

static constexpr float P_EXP = 0.8f;
static constexpr float Q_EXP = 2.0f;
static constexpr float EPS_C = 0.01f;

// ---------------- counts -> acc ----------------
__global__ void k_counts(const int* __restrict__ lab, float* __restrict__ accv){
  __shared__ int cnt[CC];
  int t = threadIdx.x;
  for (int i=t;i<CC;i+=256) cnt[i]=0;
  __syncthreads();
  for (int n=t;n<NN;n+=256) atomicAdd(&cnt[lab[n]],1);
  __syncthreads();
  for (int i=t;i<CC;i+=256) accv[i] = fmaxf((float)cnt[i],1.0f);
}

// ---------------- (c,l) augmentation table ----------------
// tbl[l*CC+c] = 0.5*lam*(Wc-Wl)^T CV_l (Wc-Wl) + lam*(Wc-Wl)·(mt_l-ms_l)
// grid: (CC, 8) blocks; block handles a-chunk [a0,a0+32); partial sums via atomicAdd.
__global__ __launch_bounds__(256) void k_table(
    const float* __restrict__ W, const float* __restrict__ CV,
    const float* __restrict__ ms, const float* __restrict__ mt,
    const float* __restrict__ lamp, float* __restrict__ tbl)
{
  const int l  = blockIdx.x;
  const int a0 = blockIdx.y * 32;
  const int c  = threadIdx.x;
  const int cc = c < CC ? c : CC-1;   // avoid OOB reads for pad threads
  const float lam = lamp[0];
  const float* Wc = W + cc*AA;
  const float* Wl = W + l*AA;

  float ea[32];
  float shift_p = 0.f;
  #pragma unroll
  for (int i4=0;i4<8;i4++){
    float4 wc = *(const float4*)(Wc + a0 + i4*4);
    float4 wl = *(const float4*)(Wl + a0 + i4*4);
    float4 dt = *(const float4*)(mt + l*AA + a0 + i4*4);
    float4 ds = *(const float4*)(ms + l*AA + a0 + i4*4);
    ea[i4*4+0] = wc.x - wl.x;
    ea[i4*4+1] = wc.y - wl.y;
    ea[i4*4+2] = wc.z - wl.z;
    ea[i4*4+3] = wc.w - wl.w;
    shift_p = fmaf(ea[i4*4+0], dt.x - ds.x, shift_p);
    shift_p = fmaf(ea[i4*4+1], dt.y - ds.y, shift_p);
    shift_p = fmaf(ea[i4*4+2], dt.z - ds.z, shift_p);
    shift_p = fmaf(ea[i4*4+3], dt.w - ds.w, shift_p);
  }

  float qf = 0.f;
  for (int bj=0; bj<8; ++bj){
    const int b0 = bj*32;
    float eb[32];
    #pragma unroll
    for (int j4=0;j4<8;j4++){
      float4 wc = *(const float4*)(Wc + b0 + j4*4);
      float4 wl = *(const float4*)(Wl + b0 + j4*4);
      eb[j4*4+0]=wc.x-wl.x; eb[j4*4+1]=wc.y-wl.y;
      eb[j4*4+2]=wc.z-wl.z; eb[j4*4+3]=wc.w-wl.w;
    }
    const float* cvb = CV + ((size_t)l*AA + a0)*AA + b0;
    #pragma unroll
    for (int i=0;i<32;i++){
      const float* r = cvb + (size_t)i*AA;   // wave-uniform -> scalar loads
      float s0=0.f,s1=0.f,s2=0.f,s3=0.f;
      #pragma unroll
      for (int j=0;j<32;j+=4){
        float4 cv4 = *(const float4*)(r + j);
        s0 = fmaf(cv4.x, eb[j+0], s0);
        s1 = fmaf(cv4.y, eb[j+1], s1);
        s2 = fmaf(cv4.z, eb[j+2], s2);
        s3 = fmaf(cv4.w, eb[j+3], s3);
      }
      qf = fmaf(ea[i], (s0+s1)+(s2+s3), qf);
    }
  }
  if (c < CC)
    atomicAdd(&tbl[l*CC+c], 0.5f*lam*qf + lam*shift_p);
}

// ---------------- per-row seesaw loss (1 wave per row) ----------------
__global__ __launch_bounds__(64) void k_rows(
    const float* __restrict__ ys, const int* __restrict__ lab,
    const float* __restrict__ accv, const float* __restrict__ tbl,
    float* __restrict__ nll)
{
  const int n    = blockIdx.x;
  const int lane = threadIdx.x;
  const int l    = lab[n];
  const float acc_l = accv[l];
  const float log_acc_l = logf(acc_l);

  float z[4];
  float m = -1e30f;
  #pragma unroll
  for (int k=0;k<4;k++){
    int cidx = k*64 + lane;
    float zz = (cidx < CC) ? (ys[n*CC+cidx] + tbl[l*CC+cidx]) : -1e30f;
    z[k] = zz;
    m = fmaxf(m, zz);
  }
  for (int o=32;o;o>>=1) m = fmaxf(m, __shfl_xor(m, o));

  float se = 0.f;
  #pragma unroll
  for (int k=0;k<4;k++){
    int cidx = k*64 + lane;
    if (cidx < CC) se += expf(z[k]-m);
  }
  for (int o=32;o;o>>=1) se += __shfl_xor(se, o);
  const float L0 = m + logf(se);            // logsumexp of z

  // z at label l
  const int kl = l >> 6, ll = l & 63;
  float zsel = (kl==0)? z[0] : (kl==1? z[1] : (kl==2? z[2] : z[3]));
  const float zl = __shfl(zsel, ll);
  const float logden = fmaxf(zl - L0, logf(EPS_C));  // log(max(self, EPS))

  float lg[4];
  float m2 = -1e30f;
  #pragma unroll
  for (int k=0;k<4;k++){
    int cidx = k*64 + lane;
    float lz = -1e30f;
    if (cidx < CC){
      lz = z[k];
      if (cidx != l){
        float lratio = (z[k] - L0) - logden;           // log(score/denom)
        float lcomp  = (lratio > 0.f) ? Q_EXP*lratio : 0.f;
        float accc   = accv[cidx];
        float lmit   = (accc < acc_l) ? P_EXP*(logf(accc) - log_acc_l) : 0.f;
        lz += lcomp + lmit;
      }
    }
    lg[k] = lz;
    m2 = fmaxf(m2, lz);
  }
  for (int o=32;o;o>>=1) m2 = fmaxf(m2, __shfl_xor(m2, o));
  float se2 = 0.f;
  #pragma unroll
  for (int k=0;k<4;k++){
    int cidx = k*64 + lane;
    if (cidx < CC) se2 += expf(lg[k]-m2);
  }
  for (int o=32;o;o>>=1) se2 += __shfl_xor(se2, o);
  const float L1 = m2 + logf(se2);          // logsumexp of logits

  if (lane==0) nll[n] = L1 - zl;            // logits[l] == z[l]
}

// ---------------- mean ----------------
__global__ void k_mean(const float* __restrict__ nll, float* __restrict__ out){
  __shared__ float s[256];
  int t=threadIdx.x;
  float v=0.f;
  for (int i=t;i<NN;i+=256) v += nll[i];
  s[t]=v; __syncthreads();
  for (int o=128;o;o>>=1){ if(t<o) s[t]+=s[t+o]; __syncthreads(); }
  if (t==0) out[0] = s[0] / (float)NN;
}

extern "C" void kernel_launch(void* const* d_in, const int* in_sizes, int n_in,
                              void* d_out, int out_size, void* d_ws, size_t ws_size,
                              hipStream_t stream) {
  const float* W   = (const float*)d_in[0];
  const float* ys  = (const float*)d_in[2];
  const int*   lab = (const int*)  d_in[3];
  const float* lam = (const float*)d_in[4];
  const float* ms  = (const float*)d_in[5];
  const float* mt  = (const float*)d_in[6];
  const float* CV  = (const float*)d_in[7];

  float* ws   = (float*)d_ws;
  float* accv = ws;                  // 256 floats
  float* tbl  = ws + 256;            // CC*CC floats
  float* nll  = ws + 256 + CC*CC;    // NN floats
  float* out  = (float*)d_out;

  hipMemsetAsync(tbl, 0, CC*CC*sizeof(float), stream);
  k_counts<<<1,256,0,stream>>>(lab, accv);
  dim3 g2(CC, 8);
  k_table<<<g2,256,0,stream>>>(W, CV, ms, mt, lam, tbl);
  k_rows<<<NN,64,0,stream>>>(ys, lab, accv, tbl, nll);
  k_mean<<<1,256,0,stream>>>(nll, out);
}

// Round 2
// 91.412 us; speedup vs baseline: 3.2367x; 3.2367x over previous
//
#include <hip/hip_runtime.h>
#include <math.h>

#define NN 1024
#define CC 200
#define AA 256
#define MT 13            // ceil(200/16) m-tiles
#define MROWS 208        // padded rows of Wbf

static constexpr float P_EXP = 0.8f;
static constexpr float Q_EXP = 2.0f;
static constexpr float EPS_C = 0.01f;

typedef __attribute__((ext_vector_type(8))) short short8;
typedef __attribute__((ext_vector_type(4))) float f32x4;

static __device__ inline unsigned short f2bf(float f){
  unsigned u = __float_as_uint(f);
  unsigned r = (u + 0x7fffu + ((u >> 16) & 1u)) >> 16;
  return (unsigned short)r;
}

// ---------------- W -> bf16 (padded to 208 rows, pad = 0) ----------------
__global__ void k_wbf(const float* __restrict__ W, unsigned short* __restrict__ Wbf){
  int idx = (blockIdx.x * 256 + threadIdx.x) * 4;   // 52 blocks * 256 * 4 = 53248 = 208*256
  if (idx >= MROWS * AA) return;
  float4 w = make_float4(0.f, 0.f, 0.f, 0.f);
  if (idx < CC * AA) w = *(const float4*)(W + idx);
  Wbf[idx + 0] = f2bf(w.x);
  Wbf[idx + 1] = f2bf(w.y);
  Wbf[idx + 2] = f2bf(w.z);
  Wbf[idx + 3] = f2bf(w.w);
}

// ---------------- counts -> acc ----------------
__global__ void k_counts(const int* __restrict__ lab, float* __restrict__ accv){
  __shared__ int cnt[CC];
  int t = threadIdx.x;
  for (int i = t; i < CC; i += 256) cnt[i] = 0;
  __syncthreads();
  for (int n = t; n < NN; n += 256) atomicAdd(&cnt[lab[n]], 1);
  __syncthreads();
  for (int i = t; i < CC; i += 256) accv[i] = fmaxf((float)cnt[i], 1.0f);
}

// ---------------- shift term, initializes tbl ----------------
// tbl[l*CC+c] = lam * (W[c]-W[l]) . (mt[l]-ms[l])
__global__ __launch_bounds__(256) void k_shift(
    const float* __restrict__ W, const float* __restrict__ ms,
    const float* __restrict__ mt, const float* __restrict__ lamp,
    float* __restrict__ tbl)
{
  const int l = blockIdx.x;
  const int c = threadIdx.x;
  if (c >= CC) return;
  const float lam = lamp[0];
  float s = 0.f;
  #pragma unroll 4
  for (int k4 = 0; k4 < AA / 4; ++k4){
    float4 wc = *(const float4*)(W  + c * AA + k4 * 4);
    float4 wl = *(const float4*)(W  + l * AA + k4 * 4);
    float4 dt = *(const float4*)(mt + l * AA + k4 * 4);
    float4 ds = *(const float4*)(ms + l * AA + k4 * 4);
    s = fmaf(wc.x - wl.x, dt.x - ds.x, s);
    s = fmaf(wc.y - wl.y, dt.y - ds.y, s);
    s = fmaf(wc.z - wl.z, dt.z - ds.z, s);
    s = fmaf(wc.w - wl.w, dt.w - ds.w, s);
  }
  tbl[l * CC + c] = lam * s;
}

// ---------------- MFMA quadratic form ----------------
// grid (200 l, 4 b-chunks) x 256 threads (4 waves).
// quad[l,c] += sum_{b in chunk} (G[c,b]-G[l,b])*(W[c,b]-W[l,b]),  G = Wbf . CV_l (bf16 MFMA)
__global__ __launch_bounds__(256, 4) void k_quad(
    const float* __restrict__ W, const unsigned short* __restrict__ Wbf,
    const float* __restrict__ CV, const float* __restrict__ lamp,
    float* __restrict__ tbl)
{
  const int l  = blockIdx.x;
  const int b0 = blockIdx.y * 64;
  const int nt = threadIdx.x >> 6;       // wave id -> 16-col n-tile
  const int lane = threadIdx.x & 63;
  const int lrow = lane & 15;
  const int kgrp = lane >> 4;            // 0..3

  __shared__ float gl[64];               // G[l, b0..b0+64)
  __shared__ float qsum[4][MROWS];

  for (int i = threadIdx.x; i < 4 * MROWS; i += 256) ((float*)qsum)[i] = 0.f;

  const int   bcol = b0 + nt * 16 + lrow;          // global b for this lane
  const float wl_b = W[l * AA + bcol];             // W[l, b]
  const size_t cvbase = (size_t)l * AA * AA;

  // ---- load all 8 B-fragments (CV columns) once, keep in regs ----
  short8 bfrag[8];
  #pragma unroll
  for (int kt = 0; kt < 8; ++kt){
    float v[8];
    #pragma unroll
    for (int j = 0; j < 8; ++j){
      int a = kt * 32 + kgrp * 8 + j;
      v[j] = CV[cvbase + (size_t)a * AA + bcol];
    }
    short8 p;
    #pragma unroll
    for (int j = 0; j < 8; ++j) p[j] = (short)f2bf(v[j]);
    bfrag[kt] = p;
  }

  // ---- pass 1: the m-tile containing row l -> extract G[l, b] ----
  const int mtl = l >> 4;
  {
    f32x4 acc = {0.f, 0.f, 0.f, 0.f};
    #pragma unroll
    for (int kt = 0; kt < 8; ++kt){
      short8 af = *(const short8*)(Wbf + (size_t)(mtl * 16 + lrow) * AA + kt * 32 + kgrp * 8);
      acc = __builtin_amdgcn_mfma_f32_16x16x32_bf16(af, bfrag[kt], acc, 0, 0, 0);
    }
    const int sel = l & 15;
    if (kgrp == (sel >> 2)){
      int jj = sel & 3;
      float g = (jj == 0) ? acc[0] : (jj == 1) ? acc[1] : (jj == 2) ? acc[2] : acc[3];
      gl[nt * 16 + lrow] = g;
    }
  }
  __syncthreads();
  const float gl_b = gl[nt * 16 + lrow];

  // ---- pass 2: all m-tiles, fused diag-dot epilogue ----
  for (int mt = 0; mt < MT; ++mt){
    f32x4 acc = {0.f, 0.f, 0.f, 0.f};
    #pragma unroll
    for (int kt = 0; kt < 8; ++kt){
      short8 af = *(const short8*)(Wbf + (size_t)(mt * 16 + lrow) * AA + kt * 32 + kgrp * 8);
      acc = __builtin_amdgcn_mfma_f32_16x16x32_bf16(af, bfrag[kt], acc, 0, 0, 0);
    }
    #pragma unroll
    for (int jj = 0; jj < 4; ++jj){
      int c = mt * 16 + kgrp * 4 + jj;
      bool valid = (c < CC);
      float e = valid ? (W[c * AA + bcol] - wl_b) : 0.f;
      float v = (acc[jj] - gl_b) * e;
      #pragma unroll
      for (int o = 1; o < 16; o <<= 1) v += __shfl_xor(v, o);
      if ((lrow == 0) && valid) qsum[nt][c] += v;
    }
  }
  __syncthreads();

  const float lam = lamp[0];
  for (int c = threadIdx.x; c < CC; c += 256){
    float tot = qsum[0][c] + qsum[1][c] + qsum[2][c] + qsum[3][c];
    atomicAdd(&tbl[l * CC + c], 0.5f * lam * tot);
  }
}

// ---------------- per-row seesaw loss (1 wave per row) ----------------
__global__ __launch_bounds__(64) void k_rows(
    const float* __restrict__ ys, const int* __restrict__ lab,
    const float* __restrict__ accv, const float* __restrict__ tbl,
    float* __restrict__ nll)
{
  const int n    = blockIdx.x;
  const int lane = threadIdx.x;
  const int l    = lab[n];
  const float acc_l = accv[l];
  const float log_acc_l = logf(acc_l);

  float z[4];
  float m = -1e30f;
  #pragma unroll
  for (int k = 0; k < 4; k++){
    int cidx = k * 64 + lane;
    float zz = (cidx < CC) ? (ys[n * CC + cidx] + tbl[l * CC + cidx]) : -1e30f;
    z[k] = zz;
    m = fmaxf(m, zz);
  }
  for (int o = 32; o; o >>= 1) m = fmaxf(m, __shfl_xor(m, o));

  float se = 0.f;
  #pragma unroll
  for (int k = 0; k < 4; k++){
    int cidx = k * 64 + lane;
    if (cidx < CC) se += expf(z[k] - m);
  }
  for (int o = 32; o; o >>= 1) se += __shfl_xor(se, o);
  const float L0 = m + logf(se);

  const int kl = l >> 6, ll = l & 63;
  float zsel = (kl == 0) ? z[0] : (kl == 1 ? z[1] : (kl == 2 ? z[2] : z[3]));
  const float zl = __shfl(zsel, ll);
  const float logden = fmaxf(zl - L0, logf(EPS_C));

  float lg[4];
  float m2 = -1e30f;
  #pragma unroll
  for (int k = 0; k < 4; k++){
    int cidx = k * 64 + lane;
    float lz = -1e30f;
    if (cidx < CC){
      lz = z[k];
      if (cidx != l){
        float lratio = (z[k] - L0) - logden;
        float lcomp  = (lratio > 0.f) ? Q_EXP * lratio : 0.f;
        float accc   = accv[cidx];
        float lmit   = (accc < acc_l) ? P_EXP * (logf(accc) - log_acc_l) : 0.f;
        lz += lcomp + lmit;
      }
    }
    lg[k] = lz;
    m2 = fmaxf(m2, lz);
  }
  for (int o = 32; o; o >>= 1) m2 = fmaxf(m2, __shfl_xor(m2, o));
  float se2 = 0.f;
  #pragma unroll
  for (int k = 0; k < 4; k++){
    int cidx = k * 64 + lane;
    if (cidx < CC) se2 += expf(lg[k] - m2);
  }
  for (int o = 32; o; o >>= 1) se2 += __shfl_xor(se2, o);
  const float L1 = m2 + logf(se2);

  if (lane == 0) nll[n] = L1 - zl;
}

// ---------------- mean ----------------
__global__ void k_mean(const float* __restrict__ nll, float* __restrict__ out){
  __shared__ float s[256];
  int t = threadIdx.x;
  float v = 0.f;
  for (int i = t; i < NN; i += 256) v += nll[i];
  s[t] = v; __syncthreads();
  for (int o = 128; o; o >>= 1){ if (t < o) s[t] += s[t + o]; __syncthreads(); }
  if (t == 0) out[0] = s[0] / (float)NN;
}

extern "C" void kernel_launch(void* const* d_in, const int* in_sizes, int n_in,
                              void* d_out, int out_size, void* d_ws, size_t ws_size,
                              hipStream_t stream) {
  const float* W   = (const float*)d_in[0];
  const float* ys  = (const float*)d_in[2];
  const int*   lab = (const int*)  d_in[3];
  const float* lam = (const float*)d_in[4];
  const float* ms  = (const float*)d_in[5];
  const float* mt  = (const float*)d_in[6];
  const float* CV  = (const float*)d_in[7];

  float* ws   = (float*)d_ws;
  float* accv = ws;                          // 256
  float* tbl  = ws + 256;                    // 40000
  float* nll  = ws + 256 + CC * CC;          // 1024
  unsigned short* Wbf = (unsigned short*)(ws + 256 + CC * CC + NN); // 208*256 u16
  float* out  = (float*)d_out;

  k_wbf   <<<52, 256, 0, stream>>>(W, Wbf);
  k_counts<<<1, 256, 0, stream>>>(lab, accv);
  k_shift <<<CC, 256, 0, stream>>>(W, ms, mt, lam, tbl);
  dim3 gq(CC, 4);
  k_quad  <<<gq, 256, 0, stream>>>(W, Wbf, CV, lam, tbl);
  k_rows  <<<NN, 64, 0, stream>>>(ys, lab, accv, tbl, nll);
  k_mean  <<<1, 256, 0, stream>>>(nll, out);
}

// Round 3
// 78.459 us; speedup vs baseline: 3.7711x; 1.1651x over previous
//
#include <hip/hip_runtime.h>
#include <math.h>

#define NN 1024
#define CC 200
#define AA 256
#define MT 13            // ceil(200/16) m-tiles
#define MROWS 208        // padded rows of Wbf

static constexpr float P_EXP = 0.8f;
static constexpr float Q_EXP = 2.0f;
static constexpr float EPS_C = 0.01f;

typedef __attribute__((ext_vector_type(8))) short short8;
typedef __attribute__((ext_vector_type(4))) float f32x4;

static __device__ inline unsigned short f2bf(float f){
  unsigned u = __float_as_uint(f);
  unsigned r = (u + 0x7fffu + ((u >> 16) & 1u)) >> 16;
  return (unsigned short)r;
}

// ---------------- W -> bf16 (padded to 208 rows, pad = 0) ----------------
__global__ void k_wbf(const float* __restrict__ W, unsigned short* __restrict__ Wbf){
  int idx = (blockIdx.x * 256 + threadIdx.x) * 4;   // 52 blocks: 208*256 elems
  if (idx >= MROWS * AA) return;
  float4 w = make_float4(0.f, 0.f, 0.f, 0.f);
  if (idx < CC * AA) w = *(const float4*)(W + idx);
  Wbf[idx + 0] = f2bf(w.x);
  Wbf[idx + 1] = f2bf(w.y);
  Wbf[idx + 2] = f2bf(w.z);
  Wbf[idx + 3] = f2bf(w.w);
}

// ---------------- counts -> acc ----------------
__global__ void k_counts(const int* __restrict__ lab, float* __restrict__ accv){
  __shared__ int cnt[CC];
  int t = threadIdx.x;
  for (int i = t; i < CC; i += 256) cnt[i] = 0;
  __syncthreads();
  for (int n = t; n < NN; n += 256) atomicAdd(&cnt[lab[n]], 1);
  __syncthreads();
  for (int i = t; i < CC; i += 256) accv[i] = fmaxf((float)cnt[i], 1.0f);
}

// ---------------- MFMA quadratic form + shift, fused ----------------
// M[c,a] = sum_b W[c,b] CV_l[a,b]   (B-operand = CV^T: contiguous loads)
// quad[l,c] = sum_a (M[c,a]-M[l,a]) * E[c,a],  E = W_c - W_l
// shift[l,c] = sum_a E[c,a] * dm[l,a]          (added by bh==0 blocks only)
// grid (200 l, 4 a-chunks, 2 b-halves) x 256 threads (4 waves, 16 a-cols each).
__global__ __launch_bounds__(256) void k_quad(
    const float* __restrict__ W, const unsigned short* __restrict__ Wbf,
    const float* __restrict__ CV, const float* __restrict__ ms,
    const float* __restrict__ mtgt, const float* __restrict__ lamp,
    float* __restrict__ tbl)
{
  const int l    = blockIdx.x;
  const int a0   = blockIdx.y * 64;      // n-dim chunk (a)
  const int bh   = blockIdx.z;           // K half: b in [bh*128, bh*128+128)
  const int nt   = threadIdx.x >> 6;     // wave id -> 16-col a-tile
  const int lane = threadIdx.x & 63;
  const int lrow = lane & 15;
  const int kgrp = lane >> 4;            // 0..3

  __shared__ float gl[64];               // M[l, a0..a0+64) partial
  __shared__ float qsum[4][MROWS];
  for (int i = threadIdx.x; i < 4 * MROWS; i += 256) ((float*)qsum)[i] = 0.f;

  const int   a_lane = a0 + nt * 16 + lrow;
  const float wl_a   = W[l * AA + a_lane];
  const float dm_a   = mtgt[l * AA + a_lane] - ms[l * AA + a_lane];
  const size_t cvrow = (size_t)l * AA * AA + (size_t)a_lane * AA + (size_t)bh * 128;

  // ---- B-fragments: B[k=b][n=a] = CV_l[a][b]; 8 consecutive floats per frag ----
  short8 bfrag[4];
  #pragma unroll
  for (int kt = 0; kt < 4; ++kt){
    const float* src = CV + cvrow + kt * 32 + kgrp * 8;
    float4 v0 = *(const float4*)(src);
    float4 v1 = *(const float4*)(src + 4);
    short8 p;
    p[0] = (short)f2bf(v0.x); p[1] = (short)f2bf(v0.y);
    p[2] = (short)f2bf(v0.z); p[3] = (short)f2bf(v0.w);
    p[4] = (short)f2bf(v1.x); p[5] = (short)f2bf(v1.y);
    p[6] = (short)f2bf(v1.z); p[7] = (short)f2bf(v1.w);
    bfrag[kt] = p;
  }

  const unsigned short* Wb = Wbf + bh * 128;   // b-half column offset

  // ---- pass 1: m-tile containing row l -> gl = M[l, a_lane] (partial) ----
  const int mtl = l >> 4;
  {
    f32x4 acc = {0.f, 0.f, 0.f, 0.f};
    #pragma unroll
    for (int kt = 0; kt < 4; ++kt){
      short8 af = *(const short8*)(Wb + (size_t)(mtl * 16 + lrow) * AA + kt * 32 + kgrp * 8);
      acc = __builtin_amdgcn_mfma_f32_16x16x32_bf16(af, bfrag[kt], acc, 0, 0, 0);
    }
    const int sel = l & 15;
    if (kgrp == (sel >> 2)){
      int jj = sel & 3;
      float g = (jj == 0) ? acc[0] : (jj == 1) ? acc[1] : (jj == 2) ? acc[2] : acc[3];
      gl[nt * 16 + lrow] = g;
    }
  }
  __syncthreads();
  const float gl_a = gl[nt * 16 + lrow];

  // ---- main: all m-tiles, fused diag-dot + shift epilogue ----
  for (int mt = 0; mt < MT; ++mt){
    f32x4 acc = {0.f, 0.f, 0.f, 0.f};
    #pragma unroll
    for (int kt = 0; kt < 4; ++kt){
      short8 af = *(const short8*)(Wb + (size_t)(mt * 16 + lrow) * AA + kt * 32 + kgrp * 8);
      acc = __builtin_amdgcn_mfma_f32_16x16x32_bf16(af, bfrag[kt], acc, 0, 0, 0);
    }
    #pragma unroll
    for (int jj = 0; jj < 4; ++jj){
      int c = mt * 16 + kgrp * 4 + jj;
      bool valid = (c < CC);
      float e = valid ? (W[c * AA + a_lane] - wl_a) : 0.f;
      float v = 0.5f * (acc[jj] - gl_a) * e;
      if (bh == 0) v += e * dm_a;          // shift term counted once
      #pragma unroll
      for (int o = 1; o < 16; o <<= 1) v += __shfl_xor(v, o);
      if ((lrow == 0) && valid) qsum[nt][c] += v;
    }
  }
  __syncthreads();

  const float lam = lamp[0];
  for (int c = threadIdx.x; c < CC; c += 256){
    float tot = qsum[0][c] + qsum[1][c] + qsum[2][c] + qsum[3][c];
    atomicAdd(&tbl[l * CC + c], lam * tot);
  }
}

// ---------------- per-row seesaw loss (1 wave per row) ----------------
__global__ __launch_bounds__(64) void k_rows(
    const float* __restrict__ ys, const int* __restrict__ lab,
    const float* __restrict__ accv, const float* __restrict__ tbl,
    float* __restrict__ nll)
{
  const int n    = blockIdx.x;
  const int lane = threadIdx.x;
  const int l    = lab[n];
  const float acc_l = accv[l];
  const float log_acc_l = logf(acc_l);

  float z[4];
  float m = -1e30f;
  #pragma unroll
  for (int k = 0; k < 4; k++){
    int cidx = k * 64 + lane;
    float zz = (cidx < CC) ? (ys[n * CC + cidx] + tbl[l * CC + cidx]) : -1e30f;
    z[k] = zz;
    m = fmaxf(m, zz);
  }
  for (int o = 32; o; o >>= 1) m = fmaxf(m, __shfl_xor(m, o));

  float se = 0.f;
  #pragma unroll
  for (int k = 0; k < 4; k++){
    int cidx = k * 64 + lane;
    if (cidx < CC) se += expf(z[k] - m);
  }
  for (int o = 32; o; o >>= 1) se += __shfl_xor(se, o);
  const float L0 = m + logf(se);

  const int kl = l >> 6, ll = l & 63;
  float zsel = (kl == 0) ? z[0] : (kl == 1 ? z[1] : (kl == 2 ? z[2] : z[3]));
  const float zl = __shfl(zsel, ll);
  const float logden = fmaxf(zl - L0, logf(EPS_C));

  float lg[4];
  float m2 = -1e30f;
  #pragma unroll
  for (int k = 0; k < 4; k++){
    int cidx = k * 64 + lane;
    float lz = -1e30f;
    if (cidx < CC){
      lz = z[k];
      if (cidx != l){
        float lratio = (z[k] - L0) - logden;
        float lcomp  = (lratio > 0.f) ? Q_EXP * lratio : 0.f;
        float accc   = accv[cidx];
        float lmit   = (accc < acc_l) ? P_EXP * (logf(accc) - log_acc_l) : 0.f;
        lz += lcomp + lmit;
      }
    }
    lg[k] = lz;
    m2 = fmaxf(m2, lz);
  }
  for (int o = 32; o; o >>= 1) m2 = fmaxf(m2, __shfl_xor(m2, o));
  float se2 = 0.f;
  #pragma unroll
  for (int k = 0; k < 4; k++){
    int cidx = k * 64 + lane;
    if (cidx < CC) se2 += expf(lg[k] - m2);
  }
  for (int o = 32; o; o >>= 1) se2 += __shfl_xor(se2, o);
  const float L1 = m2 + logf(se2);

  if (lane == 0) nll[n] = L1 - zl;
}

// ---------------- mean ----------------
__global__ void k_mean(const float* __restrict__ nll, float* __restrict__ out){
  __shared__ float s[256];
  int t = threadIdx.x;
  float v = 0.f;
  for (int i = t; i < NN; i += 256) v += nll[i];
  s[t] = v; __syncthreads();
  for (int o = 128; o; o >>= 1){ if (t < o) s[t] += s[t + o]; __syncthreads(); }
  if (t == 0) out[0] = s[0] / (float)NN;
}

extern "C" void kernel_launch(void* const* d_in, const int* in_sizes, int n_in,
                              void* d_out, int out_size, void* d_ws, size_t ws_size,
                              hipStream_t stream) {
  const float* W   = (const float*)d_in[0];
  const float* ys  = (const float*)d_in[2];
  const int*   lab = (const int*)  d_in[3];
  const float* lam = (const float*)d_in[4];
  const float* ms  = (const float*)d_in[5];
  const float* mt  = (const float*)d_in[6];
  const float* CV  = (const float*)d_in[7];

  float* ws   = (float*)d_ws;
  float* accv = ws;                          // 256
  float* tbl  = ws + 256;                    // 40000
  float* nll  = ws + 256 + CC * CC;          // 1024
  unsigned short* Wbf = (unsigned short*)(ws + 256 + CC * CC + NN); // 208*256 u16
  float* out  = (float*)d_out;

  hipMemsetAsync(tbl, 0, CC * CC * sizeof(float), stream);
  k_wbf   <<<52, 256, 0, stream>>>(W, Wbf);
  k_counts<<<1, 256, 0, stream>>>(lab, accv);
  dim3 gq(CC, 4, 2);
  k_quad  <<<gq, 256, 0, stream>>>(W, Wbf, CV, ms, mt, lam, tbl);
  k_rows  <<<NN, 64, 0, stream>>>(ys, lab, accv, tbl, nll);
  k_mean  <<<1, 256, 0, stream>>>(nll, out);
}